// Round 11
// baseline (368.945 us; speedup 1.0000x reference)
//
#include <hip/hip_runtime.h>

typedef _Float16 f16x8 __attribute__((ext_vector_type(8)));
typedef float f32x4 __attribute__((ext_vector_type(4)));
typedef unsigned short u16;
typedef u16 u16x8 __attribute__((ext_vector_type(8)));
typedef u16 u16x4 __attribute__((ext_vector_type(4)));

// ---------- fp16 <-> fp32 helpers ----------
__device__ __forceinline__ u16 f2h_bits(float f) {
    _Float16 h = (_Float16)f;           // RNE
    return __builtin_bit_cast(u16, h);
}
__device__ __forceinline__ float h2f(u16 b) {
    return (float)__builtin_bit_cast(_Float16, b);
}

// async global->LDS, 16B per lane (dest = wave-uniform base + lane*16).
typedef __attribute__((address_space(1))) unsigned int gu32_as1;
typedef __attribute__((address_space(3))) unsigned int lu32_as3;
__device__ __forceinline__ void gload16(const u16* g, u16* l) {
    __builtin_amdgcn_global_load_lds((gu32_as1*)g, (lu32_as3*)l, 16, 0, 0);
}

// =====================================================================
// GEMM: C[M,N] = alpha * A[M,K] * Bt[N,K]^T  (fp16 bits, k-contiguous).
//
// ROUND-11: GEMM loop byte-identical to round-9 (best verified, 211us;
// round-10's fp32-atomic epilogue regressed PV 52->92us -> reverted).
// Dispatch elimination via the standard split-K COMPLETION-COUNTER
// finalize instead (MODE 4): PV blocks write fp16 partials to P with
// plain coalesced stores (identical to the proven 52us MODE-0 path),
// then threadfence + atomicAdd on a per-(bm,bn)-tile counter (64
// counters, 4 writers each). The LAST z-block per tile reads the other
// 3 partials, adds its own acc from registers, divides by lr[row], and
// writes out fp32 — deleting the add_div4 dispatch + launch gap + 16MB
// of traffic. No spinning: non-last blocks exit. Counters zeroed by
// prep each launch. Release/acquire: fence before atomic, fence after
// observing old==3 (Guideline 16).
//
// 8-phase template (m201-faithful): 256x256 tile, BK=64, 512 threads =
// 8 waves (2M x 4N), wave tile 128x64 = acc[8][4] f32x4 via
// mfma_f32_16x16x32_f16. Iteration = 2 K-tiles (t0->buf0, t1->buf1),
// 8 phases; phase = one C-quadrant x K=64 = 16 MFMA.
// Stage schedule (uniform 1 half-tile/phase, vmcnt(6) at P4/P8 = 3
// half-tiles in flight; death/landing ledger verified in round-9):
//   P1: Ah1-buf1[t1]  P2: Bh0-buf0[t0+2]  P3: Ah0-buf0  P4: Bh1-buf0
//   P5: Ah1-buf0      P6: Bh0-buf1[t1+2]  P7: Ah0-buf1  P8: Bh1-buf1
// Phase sync: {reads; stage} BARRIER lgkmcnt(0) setprio(1) 16xMFMA
// setprio(0) [vmcnt] BARRIER.  No sched_barrier anywhere (m141).
//
// LDS (128 KiB): per matrix [buf:2][half:2][row:128][seg:8][8] u16
// (strides u16: buf 16384, half 8192, row 64, seg 8). Swizzle: LDS seg
// s at row r holds global seg s^(r&7); staged linearly (global seg
// pre-swizzled (t&7)^((t>>3)&7)); read at seg (kk*4+quad)^(l16&7).
// Bank-uniform -> conflict-free (measured 0).
//
// MODE: 0 plain store; 1 exp(alpha*s)+rowsum atomics; 2 QKV (bn<8 -> QK
// ldc=2048; bn>=8 -> V transposed into vt[1024][4096]); 4 PV+finalize
// (C = P base, NOT pre-offset by kz; c_z_stride = z stride of P).
// Requires Ksplit % 128 == 0, Ksplit/128 >= 2. gridDim.z = split-K.
// =====================================================================
#define BAR   __builtin_amdgcn_s_barrier()
#define LGK0  asm volatile("s_waitcnt lgkmcnt(0)" ::: "memory")
#define VM6   asm volatile("s_waitcnt vmcnt(6)" ::: "memory")
#define VM0   asm volatile("s_waitcnt vmcnt(0)" ::: "memory")
#define PRIO1 __builtin_amdgcn_s_setprio(1)
#define PRIO0 __builtin_amdgcn_s_setprio(0)

template <int MODE>
__global__ __launch_bounds__(512, 2) void gemm_bt(
    const u16* __restrict__ A, int lda,
    const u16* __restrict__ B, int ldb,
    u16* __restrict__ C, int ldc,
    int Ksplit, float alpha, size_t c_z_stride,
    int bnW, int bmW, int numPanelX,
    float* __restrict__ rowsum, u16* __restrict__ vt,
    float* __restrict__ outF, unsigned int* __restrict__ cnt)
{
    __shared__ __attribute__((aligned(16))) u16 As[32768];  // 64 KB
    __shared__ __attribute__((aligned(16))) u16 Bs[32768];  // 64 KB

    const int t    = threadIdx.x;        // 0..511
    const int lane = t & 63;
    const int wave = t >> 6;             // 0..7
    const int wm   = wave >> 2;          // 0..1  (128-row half)
    const int wn   = wave & 3;           // 0..3  (64-col quarter)
    const int l16  = lane & 15;
    const int quad = lane >> 4;

    // 2D-panel XCD mapping (grid x*y divisible by 8)
    const int lin = blockIdx.y * gridDim.x + blockIdx.x;
    const int xcd = lin & 7;
    const int idx = lin >> 3;
    const int px  = xcd % numPanelX;
    const int py  = xcd / numPanelX;
    const int bn  = px * bnW + idx % bnW;
    const int bm  = py * bmW + idx / bnW;

    const int kz = blockIdx.z;
    A += (size_t)kz * Ksplit;
    B += (size_t)kz * Ksplit;
    if (MODE != 4) C += (size_t)kz * c_z_stride;

    // staging addressing: thread t -> rows t>>3 and (t>>3)+64 of a half,
    // 16B seg (t&7); global seg pre-swizzled: (t&7)^((t>>3)&7).
    const int srow = t >> 3;
    const int sseg = ((t & 7) ^ ((t >> 3) & 7)) * 8;
    const u16* Ag = A + (size_t)(bm * 256 + srow) * lda + sseg;
    const u16* Bg = B + (size_t)(bn * 256 + srow) * ldb + sseg;
    u16* AsD = &As[t * 8];
    u16* BsD = &Bs[t * 8];

#define STG_A(h, bufv, kt) do {                                         \
        const u16* _s = Ag + (size_t)(h) * 128 * lda + (size_t)(kt) * 64; \
        u16* _d = AsD + (bufv) * 16384 + (h) * 8192;                    \
        gload16(_s, _d);                                                \
        gload16(_s + (size_t)64 * lda, _d + 4096);                      \
    } while (0)
#define STG_B(h, bufv, kt) do {                                         \
        const u16* _s = Bg + (size_t)(h) * 128 * ldb + (size_t)(kt) * 64; \
        u16* _d = BsD + (bufv) * 16384 + (h) * 8192;                    \
        gload16(_s, _d);                                                \
        gload16(_s + (size_t)64 * ldb, _d + 4096);                      \
    } while (0)

    // fragment read addressing: row' (in half) = sub*16 + l16 (+mh*64),
    // u16 off = row'*64 + ((kk*4+quad)^(l16&7))*8
    const int skz = l16 & 7;
    const int sk0 = (quad ^ skz) * 8;
    const int sk1 = ((4 + quad) ^ skz) * 8;
    const u16* Ab = As + wm * 8192 + l16 * 64;
    const u16* Bb = Bs + (wn >> 1) * 8192 + (wn & 1) * 4096 + l16 * 64;

#define RD_A(dst, mh, bufv) do {                                        \
        _Pragma("unroll") for (int mi = 0; mi < 4; mi++) {              \
            dst[mi][0] = *(const f16x8*)(Ab + (bufv) * 16384 +          \
                                         (mh) * 4096 + mi * 1024 + sk0);\
            dst[mi][1] = *(const f16x8*)(Ab + (bufv) * 16384 +          \
                                         (mh) * 4096 + mi * 1024 + sk1);\
        } } while (0)
#define RD_B(dst, nh, bufv) do {                                        \
        _Pragma("unroll") for (int nj = 0; nj < 2; nj++) {              \
            dst[nj][0] = *(const f16x8*)(Bb + (bufv) * 16384 +          \
                                         (nh) * 2048 + nj * 1024 + sk0);\
            dst[nj][1] = *(const f16x8*)(Bb + (bufv) * 16384 +          \
                                         (nh) * 2048 + nj * 1024 + sk1);\
        } } while (0)
#define MFQ(mh, nh, Af, Bf) do {                                        \
        _Pragma("unroll") for (int mi = 0; mi < 4; mi++)                \
        _Pragma("unroll") for (int nj = 0; nj < 2; nj++)                \
        _Pragma("unroll") for (int kk = 0; kk < 2; kk++)                \
            acc[(mh)*4+mi][(nh)*2+nj] =                                 \
                __builtin_amdgcn_mfma_f32_16x16x32_f16(                 \
                    Af[mi][kk], Bf[nj][kk], acc[(mh)*4+mi][(nh)*2+nj],  \
                    0, 0, 0);                                           \
    } while (0)

    f32x4 acc[8][4] = {};
    const int NI = Ksplit >> 7;   // 2 K-tiles (BK=64) per iteration

    // prologue: buf0[0] all halves; buf1[1] Bh0, Ah0, Bh1 (Ah1 at P1)
    STG_A(0, 0, 0); STG_A(1, 0, 0); STG_B(0, 0, 0); STG_B(1, 0, 0);
    STG_B(0, 1, 1); STG_A(0, 1, 1); STG_B(1, 1, 1);
    VM6;            // buf0 complete; buf1's 3 stages in flight
    BAR;

    for (int it = 0; it < NI; ++it) {
        const int t0 = it * 2, t1 = it * 2 + 1;
        const bool nl = (it + 1 < NI);
        f16x8 a0[4][2], a1[4][2], b0[2][2], b1[2][2];

        // ---- P1 ----
        RD_A(a0, 0, 0); RD_B(b0, 0, 0);
        STG_A(1, 1, t1);                       // always: used at P7
        BAR; LGK0; PRIO1; MFQ(0, 0, a0, b0); PRIO0; BAR;
        // ---- P2 ----
        RD_B(b1, 1, 0);
        if (nl) STG_B(0, 0, t0 + 2);
        BAR; LGK0; PRIO1; MFQ(0, 1, a0, b1); PRIO0; BAR;
        // ---- P3 ----
        RD_A(a1, 1, 0);
        if (nl) STG_A(0, 0, t0 + 2);
        BAR; LGK0; PRIO1; MFQ(1, 0, a1, b0); PRIO0; BAR;
        // ---- P4 ----
        if (nl) STG_B(1, 0, t0 + 2);
        BAR; LGK0; PRIO1; MFQ(1, 1, a1, b1); PRIO0;
        if (nl) VM6; else VM0;
        BAR;
        // ---- P5 ----
        RD_A(a0, 0, 1); RD_B(b0, 0, 1);
        if (nl) STG_A(1, 0, t0 + 2);
        BAR; LGK0; PRIO1; MFQ(0, 0, a0, b0); PRIO0; BAR;
        // ---- P6 ----
        RD_B(b1, 1, 1);
        if (nl) STG_B(0, 1, t1 + 2);
        BAR; LGK0; PRIO1; MFQ(0, 1, a0, b1); PRIO0; BAR;
        // ---- P7 ----
        RD_A(a1, 1, 1);
        if (nl) STG_A(0, 1, t1 + 2);
        BAR; LGK0; PRIO1; MFQ(1, 0, a1, b0); PRIO0; BAR;
        // ---- P8 ----
        if (nl) STG_B(1, 1, t1 + 2);
        BAR; LGK0; PRIO1; MFQ(1, 1, a1, b1); PRIO0;
        if (nl) VM6; else VM0;
        BAR;
    }
#undef STG_A
#undef STG_B
#undef RD_A
#undef RD_B
#undef MFQ

    // epilogue: C/D layout col = lane&15, row = quad*4 + reg
    const int crow = bm * 256 + wm * 128 + quad * 4;
    const int ccol = bn * 256 + wn * 64 + l16;

    if (MODE == 1) {
        float rs[8][4];
#pragma unroll
        for (int mi = 0; mi < 8; mi++)
#pragma unroll
            for (int r = 0; r < 4; r++) rs[mi][r] = 0.f;
#pragma unroll
        for (int mi = 0; mi < 8; mi++) {
#pragma unroll
            for (int ni = 0; ni < 4; ni++) {
#pragma unroll
                for (int r = 0; r < 4; r++) {
                    float e = __expf(acc[mi][ni][r] * alpha);
                    rs[mi][r] += e;
                    C[(size_t)(crow + mi * 16 + r) * ldc + (ccol + ni * 16)] = f2h_bits(e);
                }
            }
        }
#pragma unroll
        for (int mi = 0; mi < 8; mi++) {
#pragma unroll
            for (int r = 0; r < 4; r++) {
                float s = rs[mi][r];
#pragma unroll
                for (int o = 1; o < 16; o <<= 1) s += __shfl_xor(s, o);
                if (l16 == 0)
                    atomicAdd(&rowsum[crow + mi * 16 + r], s);
            }
        }
    } else if (MODE == 2 && bn >= 8) {
        // V tile -> write transposed into vt[1024][4096]
#pragma unroll
        for (int ni = 0; ni < 4; ni++) {
            const int cV = (bn - 8) * 256 + wn * 64 + ni * 16 + l16;
#pragma unroll
            for (int mi = 0; mi < 8; mi++) {
                u16x4 o;
#pragma unroll
                for (int r = 0; r < 4; r++) o[r] = f2h_bits(acc[mi][ni][r]);
                *(u16x4*)(vt + (size_t)cV * 4096 + crow + mi * 16) = o;
            }
        }
    } else if (MODE == 4) {
        // ---- split-K finalize via completion counter ----
        // 1) write own fp16 partial (same plain stores as MODE 0)
        u16* Pown = C + (size_t)kz * c_z_stride;
#pragma unroll
        for (int mi = 0; mi < 8; mi++)
#pragma unroll
            for (int ni = 0; ni < 4; ni++)
#pragma unroll
                for (int r = 0; r < 4; r++)
                    Pown[(size_t)(crow + mi * 16 + r) * ldc + (ccol + ni * 16)] =
                        f2h_bits(acc[mi][ni][r]);
        // 2) release: make partial visible, then count arrival
        __threadfence();
        __syncthreads();
        int* flag = (int*)As;   // LDS reuse (K-loop fully drained)
        if (t == 0)
            flag[0] = (atomicAdd(&cnt[bm * 4 + bn], 1u) == 3u) ? 1 : 0;
        __syncthreads();
        if (flag[0]) {
            // 3) acquire, then sum 3 foreign partials + own acc, divide
            __threadfence();
#pragma unroll
            for (int mi = 0; mi < 8; mi++) {
#pragma unroll
                for (int r = 0; r < 4; r++) {
                    const int row = crow + mi * 16 + r;
                    const float inv = 1.0f / rowsum[row];
#pragma unroll
                    for (int ni = 0; ni < 4; ni++) {
                        const int col = ccol + ni * 16;
                        float s = acc[mi][ni][r];
#pragma unroll
                        for (int z = 0; z < 4; z++)
                            if (z != kz)
                                s += h2f(C[(size_t)z * c_z_stride +
                                           (size_t)row * ldc + col]);
                        outF[(size_t)row * ldc + col] = s * inv;
                    }
                }
            }
        }
    } else {
#pragma unroll
        for (int mi = 0; mi < 8; mi++)
#pragma unroll
            for (int ni = 0; ni < 4; ni++)
#pragma unroll
                for (int r = 0; r < 4; r++)
                    C[(size_t)(crow + mi * 16 + r) * ldc + (ccol + ni * 16)] =
                        f2h_bits(acc[mi][ni][r] * alpha);
    }
}

// =====================================================================
// prep: fused cast_to_f16 + transpose_w3 + zero(lr,cnt) in ONE launch.
// grid.x = 4096 (cast) + 3072 (transpose, 3 z x 1024 tiles) + 4 (zero).
// 256 threads. Each block takes exactly one branch (uniform per block).
// =====================================================================
__global__ __launch_bounds__(256) void prep(
    const float* __restrict__ x, u16* __restrict__ xb,
    const float* __restrict__ W0, const float* __restrict__ W1,
    const float* __restrict__ W2, u16* __restrict__ Wt,
    float* __restrict__ lr, unsigned int* __restrict__ cnt)
{
    __shared__ float tile[32][33];
    const int bid = blockIdx.x;
    const int t   = threadIdx.x;

    if (bid < 4096) {
        // cast x fp32 -> fp16 bits, 4 elems/thread (4096*1024 total)
        int i = (bid * 256 + t) * 4;
        float4 v = *(const float4*)(x + i);
        ushort4 o;
        o.x = f2h_bits(v.x);
        o.y = f2h_bits(v.y);
        o.z = f2h_bits(v.z);
        o.w = f2h_bits(v.w);
        *(ushort4*)(xb + i) = o;
    } else if (bid < 4096 + 3072) {
        // transpose-cast W[z] 32x32 tile
        const int b   = bid - 4096;
        const int z   = b >> 10;
        const int rem = b & 1023;
        const float* in = (z == 0) ? W0 : (z == 1) ? W1 : W2;
        u16* o = Wt + (size_t)z * 1024 * 1024;
        const int bx = (rem & 31) * 32;
        const int by = (rem >> 5) * 32;
        const int tx = t & 31, ty = t >> 5;   // 32 x 8
#pragma unroll
        for (int j = 0; j < 4; j++)
            tile[ty + j * 8][tx] = in[(size_t)(by + ty + j * 8) * 1024 + bx + tx];
        __syncthreads();
#pragma unroll
        for (int j = 0; j < 4; j++)
            o[(size_t)(bx + ty + j * 8) * 1024 + by + tx] = f2h_bits(tile[tx][ty + j * 8]);
    } else {
        // zero lr (4096 floats) + cnt (64 u32, first zero-block only)
        const int zb = bid - 4096 - 3072;
        int i = (zb * 256 + t) * 4;
        *(float4*)(lr + i) = float4{0.f, 0.f, 0.f, 0.f};
        if (zb == 0 && t < 64) cnt[t] = 0u;
    }
}

// =====================================================================
// launch
//
// Workspace liveness (MiB):
//   xb [0,8)    live 1-2          Wt [8,14)  live 1-2
//   QK [14,30)  live 2-3          Vt [64,72) live 2-4
//   Sb [32,64)  live 3-4          lr [72,+16K) zero 1, atomics 3, read 4
//   P  [0,32)   written+read 4 (xb/Wt/QK dead)   cnt [72M+16K,+256B)
// =====================================================================
extern "C" void kernel_launch(void* const* d_in, const int* in_sizes, int n_in,
                              void* d_out, int out_size, void* d_ws, size_t ws_size,
                              hipStream_t stream)
{
    (void)in_sizes; (void)n_in; (void)out_size; (void)ws_size;
    const float* x  = (const float*)d_in[0];
    const float* Wq = (const float*)d_in[1];
    const float* Wk = (const float*)d_in[2];
    const float* Wv = (const float*)d_in[3];
    float* out = (float*)d_out;
    char* ws = (char*)d_ws;

    u16* xb  = (u16*)(ws);                              //  8 MiB
    u16* Wt  = (u16*)(ws + ((size_t)8  << 20));         //  6 MiB
    u16* QK  = (u16*)(ws + ((size_t)14 << 20));         // 16 MiB [4096][2048]
    u16* Sb  = (u16*)(ws + ((size_t)32 << 20));         // 32 MiB [4096][4096]
    u16* Vt  = (u16*)(ws + ((size_t)64 << 20));         //  8 MiB [1024][4096]
    float* lr = (float*)(ws + ((size_t)72 << 20));      // 16 KiB row sums
    unsigned int* cnt = (unsigned int*)(ws + ((size_t)72 << 20) + 16384); // 256 B
    u16* P   = (u16*)(ws);                              // 32 MiB: 4 x [4096][1024]

    const int S = 4096, D = 1024;

    // 1) fused prep: cast x, transpose-cast W's, zero lr + cnt
    prep<<<4096 + 3072 + 4, 256, 0, stream>>>(x, xb, Wq, Wk, Wv, Wt, lr, cnt);

    // 2) [Q|K] = x @ [Wq|Wk], V^T written directly (M=4096, N=3072, K=1024)
    //    grid 12x16=192 blocks; panels: bnW=3, bmW=8, numPanelX=4
    gemm_bt<2><<<dim3(12, 16, 1), 512, 0, stream>>>(
        xb, D, Wt, D, QK, 2048, D, 1.0f, 0, 3, 8, 4, nullptr, Vt,
        nullptr, nullptr);

    // 3) Sb = exp((Q @ K^T)/32) + rowsum atomics  (M=N=4096, K=1024)
    //    grid 16x16=256 blocks; panels: bnW=4, bmW=8, numPanelX=4
    gemm_bt<1><<<dim3(16, 16, 1), 512, 0, stream>>>(
        QK, 2048, QK + 1024, 2048, Sb, S, D, 0.03125f, 0, 4, 8, 4, lr, nullptr,
        nullptr, nullptr);

    // 4) P[z] = expS @ V partials + last-block finalize into out
    //    (M=4096, N=1024, split-K=4 of K=4096). grid 4x16x4.
    gemm_bt<4><<<dim3(4, 16, 4), 512, 0, stream>>>(
        Sb, S, Vt, S, P, D, 1024, 1.0f, (size_t)S * D, 1, 8, 4, lr, nullptr,
        out, cnt);
}

// Round 13
// 208.442 us; speedup vs baseline: 1.7700x; 1.7700x over previous
//
#include <hip/hip_runtime.h>

typedef _Float16 f16x8 __attribute__((ext_vector_type(8)));
typedef float f32x4 __attribute__((ext_vector_type(4)));
typedef unsigned short u16;
typedef u16 u16x8 __attribute__((ext_vector_type(8)));
typedef u16 u16x4 __attribute__((ext_vector_type(4)));

// ---------- fp16 <-> fp32 helpers ----------
__device__ __forceinline__ u16 f2h_bits(float f) {
    _Float16 h = (_Float16)f;           // RNE
    return __builtin_bit_cast(u16, h);
}
__device__ __forceinline__ float h2f(u16 b) {
    return (float)__builtin_bit_cast(_Float16, b);
}

// async global->LDS, 16B per lane (dest = wave-uniform base + lane*16).
typedef __attribute__((address_space(1))) unsigned int gu32_as1;
typedef __attribute__((address_space(3))) unsigned int lu32_as3;
__device__ __forceinline__ void gload16(const u16* g, u16* l) {
    __builtin_amdgcn_global_load_lds((gu32_as1*)g, (lu32_as3*)l, 16, 0, 0);
}

// =====================================================================
// GEMM: C[M,N] = alpha * A[M,K] * Bt[N,K]^T  (fp16 bits, k-contiguous).
//
// FINAL (round-12 resubmit; acquisition timed out, never ran): exact
// revert to round-9, the session's verified best (211.0us). Round-10
// (fp32-atomic epilogue: PV 52->92us) and round-11 (completion-counter
// finalize: PV 52->213us, cold cross-XCD scalar partial reads) both
// regressed and are reverted; the separate BW-bound add_div4 (~8us on
// 48MB ~= 7.6us BW floor) is optimal.
//
// GEMM loop: m201-faithful 8-phase template. Nine structural variants
// (rounds 0-9) all pin at ~52us/dispatch ~= 655 TF, MfmaUtil 20-25% —
// schedule, staging instruction, occupancy, MFMA shape, swizzle and
// prefetch depth all isolated and falsified as levers. This is the
// structure's attractor on this problem.
//
// 256x256 tile, BK=64, 512 threads = 8 waves (2M x 4N), wave tile
// 128x64 = acc[8][4] f32x4 via mfma_f32_16x16x32_f16. Iteration =
// 2 K-tiles (t0->buf0, t1->buf1), 8 phases; phase = one C-quadrant x
// K=64 = 16 MFMA. Stage schedule (1 half-tile/phase, vmcnt(6) at P4/P8
// = 3 half-tiles in flight; death/landing ledger in round-9 notes):
//   P1: Ah1-buf1[t1]  P2: Bh0-buf0[t0+2]  P3: Ah0-buf0  P4: Bh1-buf0
//   P5: Ah1-buf0      P6: Bh0-buf1[t1+2]  P7: Ah0-buf1  P8: Bh1-buf1
// Phase sync: {reads; stage} BARRIER lgkmcnt(0) setprio(1) 16xMFMA
// setprio(0) [vmcnt] BARRIER.  No sched_barrier anywhere (m141).
//
// LDS (128 KiB): per matrix [buf:2][half:2][row:128][seg:8][8] u16
// (strides u16: buf 16384, half 8192, row 64, seg 8). Swizzle: LDS seg
// s at row r holds global seg s^(r&7); staged linearly (global seg
// pre-swizzled (t&7)^((t>>3)&7)); read at seg (kk*4+quad)^(l16&7).
// Bank-uniform -> conflict-free (measured 0 all session).
//
// MODE: 0 plain store; 1 exp(alpha*s)+rowsum atomics; 2 QKV (bn<8 -> QK
// ldc=2048; bn>=8 -> V transposed into vt[1024][4096]).
// Requires Ksplit % 128 == 0, Ksplit/128 >= 2. gridDim.z = split-K.
// =====================================================================
#define BAR   __builtin_amdgcn_s_barrier()
#define LGK0  asm volatile("s_waitcnt lgkmcnt(0)" ::: "memory")
#define VM6   asm volatile("s_waitcnt vmcnt(6)" ::: "memory")
#define VM0   asm volatile("s_waitcnt vmcnt(0)" ::: "memory")
#define PRIO1 __builtin_amdgcn_s_setprio(1)
#define PRIO0 __builtin_amdgcn_s_setprio(0)

template <int MODE>
__global__ __launch_bounds__(512, 2) void gemm_bt(
    const u16* __restrict__ A, int lda,
    const u16* __restrict__ B, int ldb,
    u16* __restrict__ C, int ldc,
    int Ksplit, float alpha, size_t c_z_stride,
    int bnW, int bmW, int numPanelX,
    float* __restrict__ rowsum, u16* __restrict__ vt)
{
    __shared__ __attribute__((aligned(16))) u16 As[32768];  // 64 KB
    __shared__ __attribute__((aligned(16))) u16 Bs[32768];  // 64 KB

    const int t    = threadIdx.x;        // 0..511
    const int lane = t & 63;
    const int wave = t >> 6;             // 0..7
    const int wm   = wave >> 2;          // 0..1  (128-row half)
    const int wn   = wave & 3;           // 0..3  (64-col quarter)
    const int l16  = lane & 15;
    const int quad = lane >> 4;

    // 2D-panel XCD mapping (grid x*y divisible by 8)
    const int lin = blockIdx.y * gridDim.x + blockIdx.x;
    const int xcd = lin & 7;
    const int idx = lin >> 3;
    const int px  = xcd % numPanelX;
    const int py  = xcd / numPanelX;
    const int bn  = px * bnW + idx % bnW;
    const int bm  = py * bmW + idx / bnW;

    const int kz = blockIdx.z;
    A += (size_t)kz * Ksplit;
    B += (size_t)kz * Ksplit;
    C += (size_t)kz * c_z_stride;

    // staging addressing: thread t -> rows t>>3 and (t>>3)+64 of a half,
    // 16B seg (t&7); global seg pre-swizzled: (t&7)^((t>>3)&7).
    const int srow = t >> 3;
    const int sseg = ((t & 7) ^ ((t >> 3) & 7)) * 8;
    const u16* Ag = A + (size_t)(bm * 256 + srow) * lda + sseg;
    const u16* Bg = B + (size_t)(bn * 256 + srow) * ldb + sseg;
    u16* AsD = &As[t * 8];
    u16* BsD = &Bs[t * 8];

#define STG_A(h, bufv, kt) do {                                         \
        const u16* _s = Ag + (size_t)(h) * 128 * lda + (size_t)(kt) * 64; \
        u16* _d = AsD + (bufv) * 16384 + (h) * 8192;                    \
        gload16(_s, _d);                                                \
        gload16(_s + (size_t)64 * lda, _d + 4096);                      \
    } while (0)
#define STG_B(h, bufv, kt) do {                                         \
        const u16* _s = Bg + (size_t)(h) * 128 * ldb + (size_t)(kt) * 64; \
        u16* _d = BsD + (bufv) * 16384 + (h) * 8192;                    \
        gload16(_s, _d);                                                \
        gload16(_s + (size_t)64 * ldb, _d + 4096);                      \
    } while (0)

    // fragment read addressing: row' (in half) = sub*16 + l16 (+mh*64),
    // u16 off = row'*64 + ((kk*4+quad)^(l16&7))*8
    const int skz = l16 & 7;
    const int sk0 = (quad ^ skz) * 8;
    const int sk1 = ((4 + quad) ^ skz) * 8;
    const u16* Ab = As + wm * 8192 + l16 * 64;
    const u16* Bb = Bs + (wn >> 1) * 8192 + (wn & 1) * 4096 + l16 * 64;

#define RD_A(dst, mh, bufv) do {                                        \
        _Pragma("unroll") for (int mi = 0; mi < 4; mi++) {              \
            dst[mi][0] = *(const f16x8*)(Ab + (bufv) * 16384 +          \
                                         (mh) * 4096 + mi * 1024 + sk0);\
            dst[mi][1] = *(const f16x8*)(Ab + (bufv) * 16384 +          \
                                         (mh) * 4096 + mi * 1024 + sk1);\
        } } while (0)
#define RD_B(dst, nh, bufv) do {                                        \
        _Pragma("unroll") for (int nj = 0; nj < 2; nj++) {              \
            dst[nj][0] = *(const f16x8*)(Bb + (bufv) * 16384 +          \
                                         (nh) * 2048 + nj * 1024 + sk0);\
            dst[nj][1] = *(const f16x8*)(Bb + (bufv) * 16384 +          \
                                         (nh) * 2048 + nj * 1024 + sk1);\
        } } while (0)
#define MFQ(mh, nh, Af, Bf) do {                                        \
        _Pragma("unroll") for (int mi = 0; mi < 4; mi++)                \
        _Pragma("unroll") for (int nj = 0; nj < 2; nj++)                \
        _Pragma("unroll") for (int kk = 0; kk < 2; kk++)                \
            acc[(mh)*4+mi][(nh)*2+nj] =                                 \
                __builtin_amdgcn_mfma_f32_16x16x32_f16(                 \
                    Af[mi][kk], Bf[nj][kk], acc[(mh)*4+mi][(nh)*2+nj],  \
                    0, 0, 0);                                           \
    } while (0)

    f32x4 acc[8][4] = {};
    const int NI = Ksplit >> 7;   // 2 K-tiles (BK=64) per iteration

    // prologue: buf0[0] all halves; buf1[1] Bh0, Ah0, Bh1 (Ah1 at P1)
    STG_A(0, 0, 0); STG_A(1, 0, 0); STG_B(0, 0, 0); STG_B(1, 0, 0);
    STG_B(0, 1, 1); STG_A(0, 1, 1); STG_B(1, 1, 1);
    VM6;            // buf0 complete; buf1's 3 stages in flight
    BAR;

    for (int it = 0; it < NI; ++it) {
        const int t0 = it * 2, t1 = it * 2 + 1;
        const bool nl = (it + 1 < NI);
        f16x8 a0[4][2], a1[4][2], b0[2][2], b1[2][2];

        // ---- P1 ----
        RD_A(a0, 0, 0); RD_B(b0, 0, 0);
        STG_A(1, 1, t1);                       // always: used at P7
        BAR; LGK0; PRIO1; MFQ(0, 0, a0, b0); PRIO0; BAR;
        // ---- P2 ----
        RD_B(b1, 1, 0);
        if (nl) STG_B(0, 0, t0 + 2);
        BAR; LGK0; PRIO1; MFQ(0, 1, a0, b1); PRIO0; BAR;
        // ---- P3 ----
        RD_A(a1, 1, 0);
        if (nl) STG_A(0, 0, t0 + 2);
        BAR; LGK0; PRIO1; MFQ(1, 0, a1, b0); PRIO0; BAR;
        // ---- P4 ----
        if (nl) STG_B(1, 0, t0 + 2);
        BAR; LGK0; PRIO1; MFQ(1, 1, a1, b1); PRIO0;
        if (nl) VM6; else VM0;
        BAR;
        // ---- P5 ----
        RD_A(a0, 0, 1); RD_B(b0, 0, 1);
        if (nl) STG_A(1, 0, t0 + 2);
        BAR; LGK0; PRIO1; MFQ(0, 0, a0, b0); PRIO0; BAR;
        // ---- P6 ----
        RD_B(b1, 1, 1);
        if (nl) STG_B(0, 1, t1 + 2);
        BAR; LGK0; PRIO1; MFQ(0, 1, a0, b1); PRIO0; BAR;
        // ---- P7 ----
        RD_A(a1, 1, 1);
        if (nl) STG_A(0, 1, t1 + 2);
        BAR; LGK0; PRIO1; MFQ(1, 0, a1, b0); PRIO0; BAR;
        // ---- P8 ----
        if (nl) STG_B(1, 1, t1 + 2);
        BAR; LGK0; PRIO1; MFQ(1, 1, a1, b1); PRIO0;
        if (nl) VM6; else VM0;
        BAR;
    }
#undef STG_A
#undef STG_B
#undef RD_A
#undef RD_B
#undef MFQ

    // epilogue: C/D layout col = lane&15, row = quad*4 + reg
    const int crow = bm * 256 + wm * 128 + quad * 4;
    const int ccol = bn * 256 + wn * 64 + l16;

    if (MODE == 1) {
        float rs[8][4];
#pragma unroll
        for (int mi = 0; mi < 8; mi++)
#pragma unroll
            for (int r = 0; r < 4; r++) rs[mi][r] = 0.f;
#pragma unroll
        for (int mi = 0; mi < 8; mi++) {
#pragma unroll
            for (int ni = 0; ni < 4; ni++) {
#pragma unroll
                for (int r = 0; r < 4; r++) {
                    float e = __expf(acc[mi][ni][r] * alpha);
                    rs[mi][r] += e;
                    C[(size_t)(crow + mi * 16 + r) * ldc + (ccol + ni * 16)] = f2h_bits(e);
                }
            }
        }
#pragma unroll
        for (int mi = 0; mi < 8; mi++) {
#pragma unroll
            for (int r = 0; r < 4; r++) {
                float s = rs[mi][r];
#pragma unroll
                for (int o = 1; o < 16; o <<= 1) s += __shfl_xor(s, o);
                if (l16 == 0)
                    atomicAdd(&rowsum[crow + mi * 16 + r], s);
            }
        }
    } else if (MODE == 2 && bn >= 8) {
        // V tile -> write transposed into vt[1024][4096]
#pragma unroll
        for (int ni = 0; ni < 4; ni++) {
            const int cV = (bn - 8) * 256 + wn * 64 + ni * 16 + l16;
#pragma unroll
            for (int mi = 0; mi < 8; mi++) {
                u16x4 o;
#pragma unroll
                for (int r = 0; r < 4; r++) o[r] = f2h_bits(acc[mi][ni][r]);
                *(u16x4*)(vt + (size_t)cV * 4096 + crow + mi * 16) = o;
            }
        }
    } else {
#pragma unroll
        for (int mi = 0; mi < 8; mi++)
#pragma unroll
            for (int ni = 0; ni < 4; ni++)
#pragma unroll
                for (int r = 0; r < 4; r++)
                    C[(size_t)(crow + mi * 16 + r) * ldc + (ccol + ni * 16)] =
                        f2h_bits(acc[mi][ni][r] * alpha);
    }
}

// =====================================================================
// prep: fused cast_to_f16 + transpose_w3 + zero(lr) in ONE launch.
// grid.x = 4096 (cast) + 3072 (transpose, 3 z x 1024 tiles) + 4 (zero).
// 256 threads. Each block takes exactly one branch (uniform per block).
// =====================================================================
__global__ __launch_bounds__(256) void prep(
    const float* __restrict__ x, u16* __restrict__ xb,
    const float* __restrict__ W0, const float* __restrict__ W1,
    const float* __restrict__ W2, u16* __restrict__ Wt,
    float* __restrict__ lr)
{
    __shared__ float tile[32][33];
    const int bid = blockIdx.x;
    const int t   = threadIdx.x;

    if (bid < 4096) {
        // cast x fp32 -> fp16 bits, 4 elems/thread (4096*1024 total)
        int i = (bid * 256 + t) * 4;
        float4 v = *(const float4*)(x + i);
        ushort4 o;
        o.x = f2h_bits(v.x);
        o.y = f2h_bits(v.y);
        o.z = f2h_bits(v.z);
        o.w = f2h_bits(v.w);
        *(ushort4*)(xb + i) = o;
    } else if (bid < 4096 + 3072) {
        // transpose-cast W[z] 32x32 tile
        const int b   = bid - 4096;
        const int z   = b >> 10;
        const int rem = b & 1023;
        const float* in = (z == 0) ? W0 : (z == 1) ? W1 : W2;
        u16* o = Wt + (size_t)z * 1024 * 1024;
        const int bx = (rem & 31) * 32;
        const int by = (rem >> 5) * 32;
        const int tx = t & 31, ty = t >> 5;   // 32 x 8
#pragma unroll
        for (int j = 0; j < 4; j++)
            tile[ty + j * 8][tx] = in[(size_t)(by + ty + j * 8) * 1024 + bx + tx];
        __syncthreads();
#pragma unroll
        for (int j = 0; j < 4; j++)
            o[(size_t)(bx + ty + j * 8) * 1024 + by + tx] = f2h_bits(tile[tx][ty + j * 8]);
    } else {
        // zero lr (4096 floats)
        int i = ((bid - 4096 - 3072) * 256 + t) * 4;
        *(float4*)(lr + i) = float4{0.f, 0.f, 0.f, 0.f};
    }
}

// =====================================================================
// out = (P0+P1+P2+P3)/l[row]; partials fp16, 8 elems/thread
// =====================================================================
__global__ __launch_bounds__(256) void add_div4(
    const u16* __restrict__ P, const float* __restrict__ l,
    float* __restrict__ o)
{
    const size_t zs = (size_t)4096 * 1024;
    int i = (blockIdx.x * 256 + threadIdx.x) * 8;
    float inv = 1.0f / l[i >> 10];
    float s[8] = {};
#pragma unroll
    for (int z = 0; z < 4; z++) {
        u16x8 h = *(const u16x8*)(P + z * zs + i);
#pragma unroll
        for (int j = 0; j < 8; j++) s[j] += h2f(h[j]);
    }
    float4 lo{s[0] * inv, s[1] * inv, s[2] * inv, s[3] * inv};
    float4 hi{s[4] * inv, s[5] * inv, s[6] * inv, s[7] * inv};
    *(float4*)(o + i) = lo;
    *(float4*)(o + i + 4) = hi;
}

// =====================================================================
// launch
//
// Workspace liveness (MiB):
//   xb [0,8)    live 1-2          Wt [8,14)  live 1-2
//   QK [14,30)  live 2-4          Vt [64,72) live 2-5
//   Sb [32,64)  live 4-5          lr [72,+16K) zero 1, atomics 4, read 6
//   P  [0,32)   written 5 (xb/Wt/QK dead), read 6
// =====================================================================
extern "C" void kernel_launch(void* const* d_in, const int* in_sizes, int n_in,
                              void* d_out, int out_size, void* d_ws, size_t ws_size,
                              hipStream_t stream)
{
    (void)in_sizes; (void)n_in; (void)out_size; (void)ws_size;
    const float* x  = (const float*)d_in[0];
    const float* Wq = (const float*)d_in[1];
    const float* Wk = (const float*)d_in[2];
    const float* Wv = (const float*)d_in[3];
    float* out = (float*)d_out;
    char* ws = (char*)d_ws;

    u16* xb  = (u16*)(ws);                              //  8 MiB
    u16* Wt  = (u16*)(ws + ((size_t)8  << 20));         //  6 MiB
    u16* QK  = (u16*)(ws + ((size_t)14 << 20));         // 16 MiB [4096][2048]
    u16* Sb  = (u16*)(ws + ((size_t)32 << 20));         // 32 MiB [4096][4096]
    u16* Vt  = (u16*)(ws + ((size_t)64 << 20));         //  8 MiB [1024][4096]
    float* lr = (float*)(ws + ((size_t)72 << 20));      // 16 KiB row sums
    u16* P   = (u16*)(ws);                              // 32 MiB: 4 x [4096][1024]

    const int S = 4096, D = 1024;

    // 1) fused prep: cast x, transpose-cast W's, zero lr (one launch)
    prep<<<4096 + 3072 + 4, 256, 0, stream>>>(x, xb, Wq, Wk, Wv, Wt, lr);

    // 2) [Q|K] = x @ [Wq|Wk], V^T written directly (M=4096, N=3072, K=1024)
    //    grid 12x16=192 blocks; panels: bnW=3, bmW=8, numPanelX=4
    gemm_bt<2><<<dim3(12, 16, 1), 512, 0, stream>>>(
        xb, D, Wt, D, QK, 2048, D, 1.0f, 0, 3, 8, 4, nullptr, Vt);

    // 3) Sb = exp((Q @ K^T)/32) + rowsum atomics  (M=N=4096, K=1024)
    //    grid 16x16=256 blocks; panels: bnW=4, bmW=8, numPanelX=4
    gemm_bt<1><<<dim3(16, 16, 1), 512, 0, stream>>>(
        QK, 2048, QK + 1024, 2048, Sb, S, D, 0.03125f, 0, 4, 8, 4, lr, nullptr);

    // 4) P[z] = expS @ V, split-K=4 (M=4096, N=1024, Ksplit=1024 of K=4096)
    //    grid 4x16x4; panels per z: bnW=1, bmW=8, numPanelX=4
    gemm_bt<0><<<dim3(4, 16, 4), 512, 0, stream>>>(
        Sb, S, Vt, S, P, D, 1024, 1.0f, (size_t)S * D, 1, 8, 4, nullptr, nullptr);

    // 5) out = (P0+P1+P2+P3) / l[row]
    add_div4<<<(S * D) / (8 * 256), 256, 0, stream>>>(P, lr, out);
}